// Round 1
// baseline (4126.911 us; speedup 1.0000x reference)
//
#include <hip/hip_runtime.h>
#include <cstdint>

#define BATCH 128
#define NODES 1023
#define LEAVES 512
#define IN_DIM 300
#define MEM 300

#define BM 64
#define BN 64
#define BK 20

__device__ __forceinline__ float sigf(float x) { return 1.0f / (1.0f + __expf(-x)); }
// tanh(x) = 1 - 2/(exp(2x)+1); saturates correctly for |x| large.
__device__ __forceinline__ float tanhfast(float x) { return 1.0f - 2.0f / (1.0f + __expf(2.0f * x)); }

// ---------------- Leaf kernel ----------------
// rows r = leaf*128 + b  (M = 65536); cols = mem index (N = 300)
// acc sets: 0 = i (Wfioux cols 300+c), 1 = o (600+c), 2 = u (900+c)
__global__ __launch_bounds__(256) void leaf_kernel(
    const float* __restrict__ inputs, const float* __restrict__ Wfioux,
    const float* __restrict__ b_fioux, float* __restrict__ C, float* __restrict__ H)
{
    __shared__ float As[BK][BM];
    __shared__ float Bs[3][BK][BN];

    const int t  = threadIdx.x;
    const int tx = t & 15;        // n-dim (4 cols each)
    const int ty = t >> 4;        // m-dim (4 rows each)
    const int r0 = blockIdx.x * BM;
    const int n0 = blockIdx.y * BN;

    float acc[3][4][4];
#pragma unroll
    for (int s = 0; s < 3; ++s)
#pragma unroll
        for (int i = 0; i < 4; ++i)
#pragma unroll
            for (int j = 0; j < 4; ++j) acc[s][i][j] = 0.0f;

    for (int k0 = 0; k0 < IN_DIM; k0 += BK) {
        // A tile: 64 rows x 20 k  (320 float4 loads)
        for (int e = t; e < (BM * BK / 4); e += 256) {
            int row = e / 5, q = e % 5;
            int r = r0 + row;
            int leaf = r >> 7, b = r & 127;
            const float4 v = *(const float4*)&inputs[(size_t)b * NODES * IN_DIM + leaf * IN_DIM + k0 + 4 * q];
            As[4 * q + 0][row] = v.x; As[4 * q + 1][row] = v.y;
            As[4 * q + 2][row] = v.z; As[4 * q + 3][row] = v.w;
        }
        // B tiles: 3 sets x 20 x 64 (zero-pad cols >= 300)
        for (int e = t; e < 3 * (BK * BN / 4); e += 256) {
            int s = e / 320, e2 = e % 320;
            int k = e2 / 16, q = e2 % 16;
            int col = n0 + 4 * q;
            float4 v = make_float4(0.f, 0.f, 0.f, 0.f);
            if (col < MEM)
                v = *(const float4*)&Wfioux[(size_t)(k0 + k) * 1200 + 300 * (s + 1) + col];
            *(float4*)&Bs[s][k][4 * q] = v;
        }
        __syncthreads();
#pragma unroll
        for (int k = 0; k < BK; ++k) {
            float a[4], bi[4], bo[4], bu[4];
            *(float4*)a  = *(const float4*)&As[k][4 * ty];
            *(float4*)bi = *(const float4*)&Bs[0][k][4 * tx];
            *(float4*)bo = *(const float4*)&Bs[1][k][4 * tx];
            *(float4*)bu = *(const float4*)&Bs[2][k][4 * tx];
#pragma unroll
            for (int i = 0; i < 4; ++i)
#pragma unroll
                for (int j = 0; j < 4; ++j) {
                    acc[0][i][j] += a[i] * bi[j];
                    acc[1][i][j] += a[i] * bo[j];
                    acc[2][i][j] += a[i] * bu[j];
                }
        }
        __syncthreads();
    }

    const int col = n0 + 4 * tx;
    if (col < MEM) {
#pragma unroll
        for (int i = 0; i < 4; ++i) {
            int r = r0 + 4 * ty + i;
            int leaf = r >> 7, b = r & 127;
            float cc[4], hh[4];
#pragma unroll
            for (int j = 0; j < 4; ++j) {
                float ig = sigf(acc[0][i][j] + b_fioux[300 + col + j]);
                float og = sigf(acc[1][i][j] + b_fioux[600 + col + j]);
                float ug = tanhfast(acc[2][i][j] + b_fioux[900 + col + j]);
                float c = ig * ug;
                cc[j] = c;
                hh[j] = og * tanhfast(c);
            }
            int base = (leaf * BATCH + b) * MEM + col;
            *(float4*)&C[base] = *(float4*)cc;
            *(float4*)&H[base] = *(float4*)hh;
        }
    }
}

// ---------------- Internal-node kernel (one tree level) ----------------
// rows r = j*128 + b, node = level_start + j; K = 600 over concat(H[l],H[r])
// acc sets: 0=i (Wiouh c), 1=o (Wiouh 300+c), 2=u (Wiouh 600+c),
//           3=f_left (Wfh c), 4=f_right (Wfh 300+c)
__global__ __launch_bounds__(256) void node_kernel(
    const float* __restrict__ Wiouh, const float* __restrict__ Wfh,
    const float* __restrict__ b_fioux, const int* __restrict__ left_idx,
    const int* __restrict__ right_idx, float* __restrict__ C, float* __restrict__ H,
    int level_start, float* __restrict__ outC, float* __restrict__ outH)
{
    __shared__ float As[BK][BM];
    __shared__ float Bs[5][BK][BN];

    const int t  = threadIdx.x;
    const int tx = t & 15;
    const int ty = t >> 4;
    const int r0 = blockIdx.x * BM;
    const int n0 = blockIdx.y * BN;

    float acc[5][4][4];
#pragma unroll
    for (int s = 0; s < 5; ++s)
#pragma unroll
        for (int i = 0; i < 4; ++i)
#pragma unroll
            for (int j = 0; j < 4; ++j) acc[s][i][j] = 0.0f;

    for (int k0 = 0; k0 < 2 * MEM; k0 += BK) {
        const int side = (k0 >= MEM) ? 1 : 0;     // BK=20 divides 300: whole tile one child
        const int koff = k0 - side * MEM;
        // A tile: ch_h rows
        for (int e = t; e < (BM * BK / 4); e += 256) {
            int row = e / 5, q = e % 5;
            int r = r0 + row;
            int j = r >> 7, b = r & 127;
            int node = level_start + j;
            int child = side ? right_idx[node] : left_idx[node];
            const float4 v = *(const float4*)&H[((size_t)child * BATCH + b) * MEM + koff + 4 * q];
            As[4 * q + 0][row] = v.x; As[4 * q + 1][row] = v.y;
            As[4 * q + 2][row] = v.z; As[4 * q + 3][row] = v.w;
        }
        // B tiles: 5 sets x 20 x 64
        for (int e = t; e < 5 * (BK * BN / 4); e += 256) {
            int s = e / 320, e2 = e % 320;
            int k = e2 / 16, q = e2 % 16;
            int col = n0 + 4 * q;
            float4 v = make_float4(0.f, 0.f, 0.f, 0.f);
            if (col < MEM) {
                if (s < 3) v = *(const float4*)&Wiouh[(size_t)(k0 + k) * 900 + s * 300 + col];
                else       v = *(const float4*)&Wfh[(size_t)(k0 + k) * 600 + (s - 3) * 300 + col];
            }
            *(float4*)&Bs[s][k][4 * q] = v;
        }
        __syncthreads();
#pragma unroll
        for (int k = 0; k < BK; ++k) {
            float a[4], b0[4], b1[4], b2[4], b3[4], b4[4];
            *(float4*)a  = *(const float4*)&As[k][4 * ty];
            *(float4*)b0 = *(const float4*)&Bs[0][k][4 * tx];
            *(float4*)b1 = *(const float4*)&Bs[1][k][4 * tx];
            *(float4*)b2 = *(const float4*)&Bs[2][k][4 * tx];
            *(float4*)b3 = *(const float4*)&Bs[3][k][4 * tx];
            *(float4*)b4 = *(const float4*)&Bs[4][k][4 * tx];
#pragma unroll
            for (int i = 0; i < 4; ++i)
#pragma unroll
                for (int j = 0; j < 4; ++j) {
                    acc[0][i][j] += a[i] * b0[j];
                    acc[1][i][j] += a[i] * b1[j];
                    acc[2][i][j] += a[i] * b2[j];
                    acc[3][i][j] += a[i] * b3[j];
                    acc[4][i][j] += a[i] * b4[j];
                }
        }
        __syncthreads();
    }

    const int col = n0 + 4 * tx;
    if (col < MEM) {
#pragma unroll
        for (int i = 0; i < 4; ++i) {
            int r = r0 + 4 * ty + i;
            int j = r >> 7, b = r & 127;
            int node = level_start + j;
            int li = left_idx[node], ri = right_idx[node];
            float4 cl = *(const float4*)&C[((size_t)li * BATCH + b) * MEM + col];
            float4 cr = *(const float4*)&C[((size_t)ri * BATCH + b) * MEM + col];
            const float clv[4] = {cl.x, cl.y, cl.z, cl.w};
            const float crv[4] = {cr.x, cr.y, cr.z, cr.w};
            float cc[4], hh[4];
#pragma unroll
            for (int jj = 0; jj < 4; ++jj) {
                float bf = b_fioux[col + jj];
                float ig = sigf(acc[0][i][jj] + b_fioux[300 + col + jj]);
                float og = sigf(acc[1][i][jj] + b_fioux[600 + col + jj]);
                float ug = tanhfast(acc[2][i][jj] + b_fioux[900 + col + jj]);
                float fl = sigf(acc[3][i][jj] + bf);
                float fr = sigf(acc[4][i][jj] + bf);
                float c = ig * ug + fl * clv[jj] + fr * crv[jj];
                cc[jj] = c;
                hh[jj] = og * tanhfast(c);
            }
            int base = (node * BATCH + b) * MEM + col;
            *(float4*)&C[base] = *(float4*)cc;
            *(float4*)&H[base] = *(float4*)hh;
            if (outC) {
                int ob = b * MEM + col;
                *(float4*)&outC[ob] = *(float4*)cc;
                *(float4*)&outH[ob] = *(float4*)hh;
            }
        }
    }
}

extern "C" void kernel_launch(void* const* d_in, const int* in_sizes, int n_in,
                              void* d_out, int out_size, void* d_ws, size_t ws_size,
                              hipStream_t stream) {
    const float* inputs  = (const float*)d_in[0];
    const float* Wfioux  = (const float*)d_in[1];
    const float* b_fioux = (const float*)d_in[2];
    const float* Wiouh   = (const float*)d_in[3];
    const float* Wfh     = (const float*)d_in[4];
    const int*   left_idx  = (const int*)d_in[5];
    const int*   right_idx = (const int*)d_in[6];

    float* C = (float*)d_ws;                       // [NODES][BATCH][MEM]
    float* H = C + (size_t)NODES * BATCH * MEM;    // [NODES][BATCH][MEM]
    float* out = (float*)d_out;

    dim3 blk(256);
    // leaves: M = 512*128 = 65536 rows
    leaf_kernel<<<dim3(LEAVES * BATCH / BM, (MEM + BN - 1) / BN), blk, 0, stream>>>(
        inputs, Wfioux, b_fioux, C, H);

    static const int starts[9] = {512, 768, 896, 960, 992, 1008, 1016, 1020, 1022};
    static const int sizes [9] = {256, 128,  64,  32,  16,    8,    4,    2,    1};
    for (int l = 0; l < 9; ++l) {
        bool root = (l == 8);
        node_kernel<<<dim3(sizes[l] * BATCH / BM, (MEM + BN - 1) / BN), blk, 0, stream>>>(
            Wiouh, Wfh, b_fioux, left_idx, right_idx, C, H, starts[l],
            root ? out : nullptr, root ? out + BATCH * MEM : nullptr);
    }
}

// Round 2
// 885.743 us; speedup vs baseline: 4.6593x; 4.6593x over previous
//
#include <hip/hip_runtime.h>
#include <cstdint>

#define BATCH 128
#define NODES 1023
#define LEAVES 512
#define IN_DIM 300
#define MEM 300
#define NP 320              // padded per-set N (and per-child K)
#define OUT_HALF (BATCH*MEM)

typedef __bf16 bf16x8 __attribute__((ext_vector_type(8)));
typedef short  s16x8  __attribute__((ext_vector_type(8)));
typedef float  f32x4  __attribute__((ext_vector_type(4)));

__device__ __forceinline__ short f2bf(float f) {
    unsigned u = __float_as_uint(f);
    u += 0x7fff + ((u >> 16) & 1);
    return (short)(u >> 16);
}
__device__ __forceinline__ float sigf(float x)  { return 1.0f / (1.0f + __expf(-x)); }
__device__ __forceinline__ float tanhf_(float x){ return 1.0f - 2.0f / (1.0f + __expf(2.0f * x)); }

__device__ __forceinline__ f32x4 mfma16(s16x8 a, s16x8 b, f32x4 c) {
    return __builtin_amdgcn_mfma_f32_16x16x32_bf16(
        __builtin_bit_cast(bf16x8, a), __builtin_bit_cast(bf16x8, b), c, 0, 0, 0);
}

// ---------- weight packing: B-fragment order ----------
// frag-block = (kb, s, nb): 64 lanes x 8 bf16; lane l holds B[k=kb*32+(l>>4)*8+j][n=nb*16+(l&15)]
__global__ __launch_bounds__(256) void pack_node_w(
    const float* __restrict__ Wiouh, const float* __restrict__ Wfh, short* __restrict__ Wpk)
{
    int gid = blockIdx.x * 256 + threadIdx.x;           // 2000 frags * 64 lanes
    if (gid >= 2000 * 64) return;
    int fb = gid >> 6, l = gid & 63;
    int kb = fb / 100, rem = fb % 100, s = rem / 20, nb = rem % 20;
    int n = nb * 16 + (l & 15);
    int kbase = kb * 32 + (l >> 4) * 8;                 // k' in [0,640)
    short v[8];
#pragma unroll
    for (int j = 0; j < 8; ++j) {
        int kp = kbase + j;
        int side = kp >= NP;
        int kk = kp - side * NP;
        float f = 0.0f;
        if (kk < MEM && n < MEM) {
            int k = side * MEM + kk;
            f = (s < 3) ? Wiouh[(size_t)k * 900 + s * 300 + n]
                        : Wfh[(size_t)k * 600 + (s - 3) * 300 + n];
        }
        v[j] = f2bf(f);
    }
    *(s16x8*)&Wpk[(size_t)gid * 8] = *(s16x8*)v;
}

__global__ __launch_bounds__(256) void pack_leaf_w(
    const float* __restrict__ Wfioux, short* __restrict__ Wpk)
{
    int gid = blockIdx.x * 256 + threadIdx.x;           // 600 frags * 64 lanes
    if (gid >= 600 * 64) return;
    int fb = gid >> 6, l = gid & 63;
    int kb = fb / 60, rem = fb % 60, s = rem / 20, nb = rem % 20;
    int n = nb * 16 + (l & 15);
    int kbase = kb * 32 + (l >> 4) * 8;                 // k' in [0,320)
    short v[8];
#pragma unroll
    for (int j = 0; j < 8; ++j) {
        int kp = kbase + j;
        float f = 0.0f;
        if (kp < IN_DIM && n < MEM)
            f = Wfioux[(size_t)kp * 1200 + (s + 1) * 300 + n];
        v[j] = f2bf(f);
    }
    *(s16x8*)&Wpk[(size_t)gid * 8] = *(s16x8*)v;
}

// ---------- leaf GEMM+gates: one leaf per block, 64-col slice per blockIdx.y ----------
// sets: 0=i, 1=o, 2=u ; K = 300 (padded 320), A = inputs fp32 -> bf16 in-reg
__global__ __launch_bounds__(256, 2) void leaf_mfma(
    const float* __restrict__ inputs, const short* __restrict__ Wpk,
    const float* __restrict__ b_fioux, float* __restrict__ C, short* __restrict__ H)
{
    __shared__ short Bs[12 * 64 * 8];                   // 12 frags = 12 KB

    const int t = threadIdx.x;
    const int l = t & 63, w = t >> 6;
    const int wm = w >> 1, wn = w & 1;
    const int lane16 = l & 15, quad = l >> 4;
    const int leaf = blockIdx.x;
    const int c0 = blockIdx.y * 64, nb0 = blockIdx.y * 4;

    f32x4 acc[3][4][2];
#pragma unroll
    for (int s = 0; s < 3; ++s)
#pragma unroll
        for (int mi = 0; mi < 4; ++mi)
#pragma unroll
            for (int ni = 0; ni < 2; ++ni) acc[s][mi][ni] = (f32x4)(0.0f);

    for (int kb = 0; kb < 10; ++kb) {
        const int k0 = kb * 32 + quad * 8;
        // A frags direct from global fp32, convert
        s16x8 a[4];
#pragma unroll
        for (int mi = 0; mi < 4; ++mi) {
            int b = wm * 64 + mi * 16 + lane16;
            const float* src = &inputs[((size_t)b * NODES + leaf) * IN_DIM + k0];
            float lo[4] = {0, 0, 0, 0}, hi[4] = {0, 0, 0, 0};
            if (k0 < IN_DIM)     *(f32x4*)lo = *(const f32x4*)src;
            if (k0 + 4 < IN_DIM) *(f32x4*)hi = *(const f32x4*)(src + 4);
            short av[8] = {f2bf(lo[0]), f2bf(lo[1]), f2bf(lo[2]), f2bf(lo[3]),
                           f2bf(hi[0]), f2bf(hi[1]), f2bf(hi[2]), f2bf(hi[3])};
            a[mi] = *(s16x8*)av;
        }
        __syncthreads();
#pragma unroll
        for (int it = 0; it < 3; ++it) {
            int c = it * 256 + t;
            int lf = c >> 6, cl = c & 63;
            int s = lf >> 2, nf = lf & 3;
            *(s16x8*)&Bs[(size_t)(lf * 64 + cl) * 8] =
                *(const s16x8*)&Wpk[((size_t)((kb * 3 + s) * 20 + nb0 + nf) * 64 + cl) * 8];
        }
        __syncthreads();
#pragma unroll
        for (int s = 0; s < 3; ++s)
#pragma unroll
            for (int ni = 0; ni < 2; ++ni) {
                s16x8 bf = *(const s16x8*)&Bs[((s * 4 + wn * 2 + ni) * 64 + l) * 8];
#pragma unroll
                for (int mi = 0; mi < 4; ++mi)
                    acc[s][mi][ni] = mfma16(a[mi], bf, acc[s][mi][ni]);
            }
    }

#pragma unroll
    for (int ni = 0; ni < 2; ++ni) {
        int col = c0 + wn * 32 + ni * 16 + lane16;
        bool valid = col < MEM;
        float bi = 0, bo = 0, bu = 0;
        if (valid) { bi = b_fioux[300 + col]; bo = b_fioux[600 + col]; bu = b_fioux[900 + col]; }
#pragma unroll
        for (int mi = 0; mi < 4; ++mi)
#pragma unroll
            for (int r = 0; r < 4; ++r) {
                int b = wm * 64 + mi * 16 + quad * 4 + r;
                size_t hIdx = ((size_t)leaf * BATCH + b) * NP + col;
                if (valid) {
                    float ig = sigf(acc[0][mi][ni][r] + bi);
                    float og = sigf(acc[1][mi][ni][r] + bo);
                    float ug = tanhf_(acc[2][mi][ni][r] + bu);
                    float c = ig * ug;
                    float h = og * tanhf_(c);
                    C[((size_t)leaf * BATCH + b) * MEM + col] = c;
                    H[hIdx] = f2bf(h);
                } else {
                    H[hIdx] = 0;
                }
            }
    }
}

// ---------- internal node GEMM+gates: one node per block ----------
// sets: 0=i, 1=o, 2=u, 3=f_left, 4=f_right ; K = 640 (2 children x 320)
__global__ __launch_bounds__(256, 2) void node_mfma(
    const short* __restrict__ Wpk, const float* __restrict__ b_fioux,
    const int* __restrict__ left_idx, const int* __restrict__ right_idx,
    float* __restrict__ C, short* __restrict__ H,
    int level_start, float* __restrict__ out)
{
    __shared__ short Bs[20 * 64 * 8];                   // 20 frags = 20 KB

    const int t = threadIdx.x;
    const int l = t & 63, w = t >> 6;
    const int wm = w >> 1, wn = w & 1;
    const int lane16 = l & 15, quad = l >> 4;
    const int node = level_start + blockIdx.x;
    const int c0 = blockIdx.y * 64, nb0 = blockIdx.y * 4;

    const int li = left_idx[node], ri = right_idx[node];
    const size_t baseL = (size_t)li * BATCH * NP;
    const size_t baseR = (size_t)ri * BATCH * NP;

    f32x4 acc[5][4][2];
#pragma unroll
    for (int s = 0; s < 5; ++s)
#pragma unroll
        for (int mi = 0; mi < 4; ++mi)
#pragma unroll
            for (int ni = 0; ni < 2; ++ni) acc[s][mi][ni] = (f32x4)(0.0f);

    for (int kb = 0; kb < 20; ++kb) {
        const int side = kb >= 10;
        const int koff = (kb - side * 10) * 32 + quad * 8;
        const short* Hb = H + (side ? baseR : baseL) + koff;
        s16x8 a[4];
#pragma unroll
        for (int mi = 0; mi < 4; ++mi)
            a[mi] = *(const s16x8*)(Hb + (size_t)(wm * 64 + mi * 16 + lane16) * NP);
        __syncthreads();
#pragma unroll
        for (int it = 0; it < 5; ++it) {
            int c = it * 256 + t;
            int lf = c >> 6, cl = c & 63;
            int s = lf >> 2, nf = lf & 3;
            *(s16x8*)&Bs[(size_t)(lf * 64 + cl) * 8] =
                *(const s16x8*)&Wpk[((size_t)((kb * 5 + s) * 20 + nb0 + nf) * 64 + cl) * 8];
        }
        __syncthreads();
#pragma unroll
        for (int s = 0; s < 5; ++s)
#pragma unroll
            for (int ni = 0; ni < 2; ++ni) {
                s16x8 bf = *(const s16x8*)&Bs[((s * 4 + wn * 2 + ni) * 64 + l) * 8];
#pragma unroll
                for (int mi = 0; mi < 4; ++mi)
                    acc[s][mi][ni] = mfma16(a[mi], bf, acc[s][mi][ni]);
            }
    }

#pragma unroll
    for (int ni = 0; ni < 2; ++ni) {
        int col = c0 + wn * 32 + ni * 16 + lane16;
        bool valid = col < MEM;
        float bff = 0, bi = 0, bo = 0, bu = 0;
        if (valid) {
            bff = b_fioux[col]; bi = b_fioux[300 + col];
            bo = b_fioux[600 + col]; bu = b_fioux[900 + col];
        }
#pragma unroll
        for (int mi = 0; mi < 4; ++mi)
#pragma unroll
            for (int r = 0; r < 4; ++r) {
                int row = wm * 64 + mi * 16 + quad * 4 + r;
                size_t hIdx = ((size_t)node * BATCH + row) * NP + col;
                if (valid) {
                    float cl = C[((size_t)li * BATCH + row) * MEM + col];
                    float cr = C[((size_t)ri * BATCH + row) * MEM + col];
                    float ig = sigf(acc[0][mi][ni][r] + bi);
                    float og = sigf(acc[1][mi][ni][r] + bo);
                    float ug = tanhf_(acc[2][mi][ni][r] + bu);
                    float fl = sigf(acc[3][mi][ni][r] + bff);
                    float fr = sigf(acc[4][mi][ni][r] + bff);
                    float c = ig * ug + fl * cl + fr * cr;
                    float h = og * tanhf_(c);
                    C[((size_t)node * BATCH + row) * MEM + col] = c;
                    H[hIdx] = f2bf(h);
                    if (out) {
                        out[row * MEM + col] = c;
                        out[OUT_HALF + row * MEM + col] = h;
                    }
                } else {
                    H[hIdx] = 0;
                }
            }
    }
}

extern "C" void kernel_launch(void* const* d_in, const int* in_sizes, int n_in,
                              void* d_out, int out_size, void* d_ws, size_t ws_size,
                              hipStream_t stream) {
    const float* inputs  = (const float*)d_in[0];
    const float* Wfioux  = (const float*)d_in[1];
    const float* b_fioux = (const float*)d_in[2];
    const float* Wiouh   = (const float*)d_in[3];
    const float* Wfh     = (const float*)d_in[4];
    const int*   left_idx  = (const int*)d_in[5];
    const int*   right_idx = (const int*)d_in[6];

    float* C   = (float*)d_ws;                              // [1023][128][300] fp32
    short* H   = (short*)(C + (size_t)NODES * BATCH * MEM); // [1023][128][320] bf16
    short* WpkN = H + (size_t)NODES * BATCH * NP;           // 2000 frag-blocks
    short* WpkL = WpkN + (size_t)2000 * 512;                // 600 frag-blocks
    float* out = (float*)d_out;

    pack_leaf_w<<<150, 256, 0, stream>>>(Wfioux, WpkL);
    pack_node_w<<<500, 256, 0, stream>>>(Wiouh, Wfh, WpkN);

    leaf_mfma<<<dim3(LEAVES, 5), 256, 0, stream>>>(inputs, WpkL, b_fioux, C, H);

    static const int starts[9] = {512, 768, 896, 960, 992, 1008, 1016, 1020, 1022};
    static const int sizes [9] = {256, 128,  64,  32,  16,    8,    4,    2,    1};
    for (int lvl = 0; lvl < 9; ++lvl) {
        bool root = (lvl == 8);
        node_mfma<<<dim3(sizes[lvl], 5), 256, 0, stream>>>(
            WpkN, b_fioux, left_idx, right_idx, C, H, starts[lvl],
            root ? out : nullptr);
    }
}

// Round 3
// 842.553 us; speedup vs baseline: 4.8981x; 1.0513x over previous
//
#include <hip/hip_runtime.h>
#include <cstdint>

#define BATCH 128
#define NODES 1023
#define LEAVES 512
#define IN_DIM 300
#define MEM 300
#define NP 320              // padded per-set N (and per-child K)
#define OUT_HALF (BATCH*MEM)

typedef __bf16 bf16x8 __attribute__((ext_vector_type(8)));
typedef short  s16x8  __attribute__((ext_vector_type(8)));
typedef short  s16x4  __attribute__((ext_vector_type(4)));
typedef float  f32x4  __attribute__((ext_vector_type(4)));

__device__ __forceinline__ short f2bf(float f) {
    unsigned u = __float_as_uint(f);
    u += 0x7fff + ((u >> 16) & 1);
    return (short)(u >> 16);
}
__device__ __forceinline__ float sigf(float x)  { return 1.0f / (1.0f + __expf(-x)); }
__device__ __forceinline__ float tanhf_(float x){ return 1.0f - 2.0f / (1.0f + __expf(2.0f * x)); }

__device__ __forceinline__ f32x4 mfma16(s16x8 a, s16x8 b, f32x4 c) {
    return __builtin_amdgcn_mfma_f32_16x16x32_bf16(
        __builtin_bit_cast(bf16x8, a), __builtin_bit_cast(bf16x8, b), c, 0, 0, 0);
}

// ---------- weight packing: B-fragment order ----------
// frag-block (kb,s,nb): 64 lanes x 8 bf16; lane l holds B[k=kb*32+(l>>4)*8+j][n=nb*16+(l&15)]
__global__ __launch_bounds__(256) void pack_node_w(
    const float* __restrict__ Wiouh, const float* __restrict__ Wfh, short* __restrict__ Wpk)
{
    int gid = blockIdx.x * 256 + threadIdx.x;           // 2000 frags * 64 lanes
    if (gid >= 2000 * 64) return;
    int fb = gid >> 6, l = gid & 63;
    int kb = fb / 100, rem = fb % 100, s = rem / 20, nb = rem % 20;
    int n = nb * 16 + (l & 15);
    int kbase = kb * 32 + (l >> 4) * 8;                 // k' in [0,640)
    short v[8];
#pragma unroll
    for (int j = 0; j < 8; ++j) {
        int kp = kbase + j;
        int side = kp >= NP;
        int kk = kp - side * NP;
        float f = 0.0f;
        if (kk < MEM && n < MEM) {
            int k = side * MEM + kk;
            f = (s < 3) ? Wiouh[(size_t)k * 900 + s * 300 + n]
                        : Wfh[(size_t)k * 600 + (s - 3) * 300 + n];
        }
        v[j] = f2bf(f);
    }
    *(s16x8*)&Wpk[(size_t)gid * 8] = *(s16x8*)v;
}

__global__ __launch_bounds__(256) void pack_leaf_w(
    const float* __restrict__ Wfioux, short* __restrict__ Wpk)
{
    int gid = blockIdx.x * 256 + threadIdx.x;           // 600 frags * 64 lanes
    if (gid >= 600 * 64) return;
    int fb = gid >> 6, l = gid & 63;
    int kb = fb / 60, rem = fb % 60, s = rem / 20, nb = rem % 20;
    int n = nb * 16 + (l & 15);
    int kbase = kb * 32 + (l >> 4) * 8;                 // k' in [0,320)
    short v[8];
#pragma unroll
    for (int j = 0; j < 8; ++j) {
        int kp = kbase + j;
        float f = 0.0f;
        if (kp < IN_DIM && n < MEM)
            f = Wfioux[(size_t)kp * 1200 + (s + 1) * 300 + n];
        v[j] = f2bf(f);
    }
    *(s16x8*)&Wpk[(size_t)gid * 8] = *(s16x8*)v;
}

// ---------- leaf-input packing: X[leaf][b][kp] bf16, kp padded to 320 ----------
__global__ __launch_bounds__(256) void pack_x(
    const float* __restrict__ inputs, short* __restrict__ X)
{
    int gid = blockIdx.x * 256 + threadIdx.x;           // 512*128*80 quads
    if (gid >= LEAVES * BATCH * (NP / 4)) return;
    int q = gid % (NP / 4);
    int rb = gid / (NP / 4);
    int b = rb % BATCH, leaf = rb / BATCH;
    short v[4] = {0, 0, 0, 0};
    if (q < IN_DIM / 4) {
        f32x4 f = *(const f32x4*)&inputs[((size_t)b * NODES + leaf) * IN_DIM + q * 4];
        v[0] = f2bf(f[0]); v[1] = f2bf(f[1]); v[2] = f2bf(f[2]); v[3] = f2bf(f[3]);
    }
    *(s16x4*)&X[(size_t)gid * 4] = *(s16x4*)v;
}

// ---------- leaf GEMM+gates: no LDS, no barriers ----------
// sets: 0=i, 1=o, 2=u ; K = 320 (padded), A = X bf16
__global__ __launch_bounds__(256, 2) void leaf_mfma(
    const short* __restrict__ X, const short* __restrict__ Wpk,
    const float* __restrict__ b_fioux, float* __restrict__ C, short* __restrict__ H)
{
    const int t = threadIdx.x;
    const int l = t & 63, w = t >> 6;
    const int wm = w >> 1, wn = w & 1;
    const int lane16 = l & 15, quad = l >> 4;
    const int leaf = blockIdx.x;
    const int c0 = blockIdx.y * 64, nb0 = blockIdx.y * 4;

    const short* Xb = X + (size_t)leaf * BATCH * NP;

    f32x4 acc[3][4][2];
#pragma unroll
    for (int s = 0; s < 3; ++s)
#pragma unroll
        for (int mi = 0; mi < 4; ++mi)
#pragma unroll
            for (int ni = 0; ni < 2; ++ni) acc[s][mi][ni] = (f32x4)(0.0f);

    for (int kb = 0; kb < 10; ++kb) {
        const int koff = kb * 32 + quad * 8;
        s16x8 a[4];
#pragma unroll
        for (int mi = 0; mi < 4; ++mi)
            a[mi] = *(const s16x8*)(Xb + (size_t)(wm * 64 + mi * 16 + lane16) * NP + koff);
#pragma unroll
        for (int s = 0; s < 3; ++s)
#pragma unroll
            for (int ni = 0; ni < 2; ++ni) {
                s16x8 bfr = *(const s16x8*)&Wpk[((size_t)((kb * 3 + s) * 20 + nb0 + wn * 2 + ni) * 64 + l) * 8];
#pragma unroll
                for (int mi = 0; mi < 4; ++mi)
                    acc[s][mi][ni] = mfma16(a[mi], bfr, acc[s][mi][ni]);
            }
    }

#pragma unroll
    for (int ni = 0; ni < 2; ++ni) {
        int col = c0 + wn * 32 + ni * 16 + lane16;
        bool valid = col < MEM;
        float bi = 0, bo = 0, bu = 0;
        if (valid) { bi = b_fioux[300 + col]; bo = b_fioux[600 + col]; bu = b_fioux[900 + col]; }
#pragma unroll
        for (int mi = 0; mi < 4; ++mi)
#pragma unroll
            for (int r = 0; r < 4; ++r) {
                int b = wm * 64 + mi * 16 + quad * 4 + r;
                size_t hIdx = ((size_t)leaf * BATCH + b) * NP + col;
                if (valid) {
                    float ig = sigf(acc[0][mi][ni][r] + bi);
                    float og = sigf(acc[1][mi][ni][r] + bo);
                    float ug = tanhf_(acc[2][mi][ni][r] + bu);
                    float c = ig * ug;
                    float h = og * tanhf_(c);
                    C[((size_t)leaf * BATCH + b) * MEM + col] = c;
                    H[hIdx] = f2bf(h);
                } else {
                    H[hIdx] = 0;
                }
            }
    }
}

// ---------- internal node GEMM+gates: no LDS, no barriers ----------
// sets: 0=i, 1=o, 2=u, 3=f_left, 4=f_right ; K = 640 (2 children x 320)
__global__ __launch_bounds__(256, 2) void node_mfma(
    const short* __restrict__ Wpk, const float* __restrict__ b_fioux,
    const int* __restrict__ left_idx, const int* __restrict__ right_idx,
    float* __restrict__ C, short* __restrict__ H,
    int level_start, float* __restrict__ out)
{
    const int t = threadIdx.x;
    const int l = t & 63, w = t >> 6;
    const int wm = w >> 1, wn = w & 1;
    const int lane16 = l & 15, quad = l >> 4;
    const int node = level_start + blockIdx.x;
    const int c0 = blockIdx.y * 64, nb0 = blockIdx.y * 4;

    const int li = left_idx[node], ri = right_idx[node];
    const short* HL = H + (size_t)li * BATCH * NP;
    const short* HR = H + (size_t)ri * BATCH * NP;

    f32x4 acc[5][4][2];
#pragma unroll
    for (int s = 0; s < 5; ++s)
#pragma unroll
        for (int mi = 0; mi < 4; ++mi)
#pragma unroll
            for (int ni = 0; ni < 2; ++ni) acc[s][mi][ni] = (f32x4)(0.0f);

    for (int kb = 0; kb < 20; ++kb) {
        const int side = kb >= 10;
        const int koff = (kb - side * 10) * 32 + quad * 8;
        const short* Hb = (side ? HR : HL) + koff;
        s16x8 a[4];
#pragma unroll
        for (int mi = 0; mi < 4; ++mi)
            a[mi] = *(const s16x8*)(Hb + (size_t)(wm * 64 + mi * 16 + lane16) * NP);
#pragma unroll
        for (int s = 0; s < 5; ++s)
#pragma unroll
            for (int ni = 0; ni < 2; ++ni) {
                s16x8 bfr = *(const s16x8*)&Wpk[((size_t)((kb * 5 + s) * 20 + nb0 + wn * 2 + ni) * 64 + l) * 8];
#pragma unroll
                for (int mi = 0; mi < 4; ++mi)
                    acc[s][mi][ni] = mfma16(a[mi], bfr, acc[s][mi][ni]);
            }
    }

#pragma unroll
    for (int ni = 0; ni < 2; ++ni) {
        int col = c0 + wn * 32 + ni * 16 + lane16;
        bool valid = col < MEM;
        float bff = 0, bi = 0, bo = 0, bu = 0;
        if (valid) {
            bff = b_fioux[col]; bi = b_fioux[300 + col];
            bo = b_fioux[600 + col]; bu = b_fioux[900 + col];
        }
#pragma unroll
        for (int mi = 0; mi < 4; ++mi)
#pragma unroll
            for (int r = 0; r < 4; ++r) {
                int row = wm * 64 + mi * 16 + quad * 4 + r;
                size_t hIdx = ((size_t)node * BATCH + row) * NP + col;
                if (valid) {
                    float cl = C[((size_t)li * BATCH + row) * MEM + col];
                    float cr = C[((size_t)ri * BATCH + row) * MEM + col];
                    float ig = sigf(acc[0][mi][ni][r] + bi);
                    float og = sigf(acc[1][mi][ni][r] + bo);
                    float ug = tanhf_(acc[2][mi][ni][r] + bu);
                    float fl = sigf(acc[3][mi][ni][r] + bff);
                    float fr = sigf(acc[4][mi][ni][r] + bff);
                    float c = ig * ug + fl * cl + fr * cr;
                    float h = og * tanhf_(c);
                    C[((size_t)node * BATCH + row) * MEM + col] = c;
                    H[hIdx] = f2bf(h);
                    if (out) {
                        out[row * MEM + col] = c;
                        out[OUT_HALF + row * MEM + col] = h;
                    }
                } else {
                    H[hIdx] = 0;
                }
            }
    }
}

extern "C" void kernel_launch(void* const* d_in, const int* in_sizes, int n_in,
                              void* d_out, int out_size, void* d_ws, size_t ws_size,
                              hipStream_t stream) {
    const float* inputs  = (const float*)d_in[0];
    const float* Wfioux  = (const float*)d_in[1];
    const float* b_fioux = (const float*)d_in[2];
    const float* Wiouh   = (const float*)d_in[3];
    const float* Wfh     = (const float*)d_in[4];
    const int*   left_idx  = (const int*)d_in[5];
    const int*   right_idx = (const int*)d_in[6];

    float* C    = (float*)d_ws;                               // [1023][128][300] fp32
    short* H    = (short*)(C + (size_t)NODES * BATCH * MEM);  // [1023][128][320] bf16
    short* WpkN = H + (size_t)NODES * BATCH * NP;             // 2000 frag-blocks
    short* WpkL = WpkN + (size_t)2000 * 512;                  // 600 frag-blocks
    short* X    = WpkL + (size_t)600 * 512;                   // [512][128][320] bf16
    float* out  = (float*)d_out;

    pack_x<<<(LEAVES * BATCH * (NP / 4) + 255) / 256, 256, 0, stream>>>(inputs, X);
    pack_leaf_w<<<150, 256, 0, stream>>>(Wfioux, WpkL);
    pack_node_w<<<500, 256, 0, stream>>>(Wiouh, Wfh, WpkN);

    leaf_mfma<<<dim3(LEAVES, 5), 256, 0, stream>>>(X, WpkL, b_fioux, C, H);

    static const int starts[9] = {512, 768, 896, 960, 992, 1008, 1016, 1020, 1022};
    static const int sizes [9] = {256, 128,  64,  32,  16,    8,    4,    2,    1};
    for (int lvl = 0; lvl < 9; ++lvl) {
        bool root = (lvl == 8);
        node_mfma<<<dim3(sizes[lvl], 5), 256, 0, stream>>>(
            WpkN, b_fioux, left_idx, right_idx, C, H, starts[lvl],
            root ? out : nullptr);
    }
}